// Round 1
// baseline (118.381 us; speedup 1.0000x reference)
//
#include <hip/hip_runtime.h>
#include <hip/hip_bf16.h>

using u16 = unsigned short;
using u32 = unsigned int;
typedef float f32x4 __attribute__((ext_vector_type(4)));
typedef __bf16 bf16x8 __attribute__((ext_vector_type(8)));

// ---- helpers ----------------------------------------------------------------
static __device__ __forceinline__ float bflo(u32 u) { return __uint_as_float(u << 16); }
static __device__ __forceinline__ float bfhi(u32 u) { return __uint_as_float(u & 0xffff0000u); }

static __device__ __forceinline__ u32 pack2(float a, float b) {
  __hip_bfloat16 ha = __float2bfloat16(a);
  __hip_bfloat16 hb = __float2bfloat16(b);
  u16 ra, rb;
  __builtin_memcpy(&ra, &ha, 2);
  __builtin_memcpy(&rb, &hb, 2);
  return (u32)ra | ((u32)rb << 16);
}

static __device__ __forceinline__ u16 f2bf(float f) {
  u32 u = __float_as_uint(f);
  u32 r = (u + 0x7fffu + ((u >> 16) & 1u)) >> 16;
  return (u16)r;
}

// ---- kernel 1: x [B,C,H,W] f32 -> xT [B,H,W,C] bf16 -------------------------
// block per (b,y): 512 blocks x 256 threads
__global__ __launch_bounds__(256) void transpose_k(const float* __restrict__ x,
                                                   u16* __restrict__ xT) {
  const int bid = blockIdx.x;
  const int b = bid >> 6, y = bid & 63;
  const int t = threadIdx.x;
  const int cg = t >> 4;   // 0..15 -> channels cg*8..cg*8+7
  const int w16 = t & 15;
  const float* xp = x + ((size_t)(b * 128) * 64 + y) * 64;  // + c*4096 + w
  u16* op = xT + ((size_t)(b * 64 + y) * 64) * 128;         // + w*128 + c
#pragma unroll
  for (int pass = 0; pass < 4; pass++) {
    int w = pass * 16 + w16;
    u32 rr[4];
#pragma unroll
    for (int jj = 0; jj < 4; jj++) {
      float a = xp[(cg * 8 + 2 * jj) * 4096 + w];
      float c = xp[(cg * 8 + 2 * jj + 1) * 4096 + w];
      rr[jj] = pack2(a, c);
    }
    uint4 r;
    r.x = rr[0]; r.y = rr[1]; r.z = rr[2]; r.w = rr[3];
    *(uint4*)(op + w * 128 + cg * 8) = r;
  }
}

// ---- kernel 2: weff[ks][n][kc] bf16 -----------------------------------------
// weff_br[o][c][tap] = sum_oc wf[o, br*84+oc] * w_br[oc][c][tap]
// ks in 0..71: br = ks>=36, ksb = ks - 36*br, tap = ksb>>2, chunk = ksb&3,
// c = chunk*32 + kc. n (=o) padded to 96.
__global__ __launch_bounds__(256) void weff_k(const float* __restrict__ w0,
                                              const float* __restrict__ w1,
                                              const float* __restrict__ wf,
                                              u16* __restrict__ weffg) {
  const int idx = blockIdx.x * 256 + threadIdx.x;  // 221184 total
  const int kc = idx & 31;
  const int rest = idx >> 5;      // ks*96 + n
  const int ks = rest / 96;
  const int n = rest - ks * 96;
  const int br = ks >= 36 ? 1 : 0;
  const int ksb = ks - br * 36;
  const int tap = ksb >> 2, chunk = ksb & 3;
  const int c = chunk * 32 + kc;
  float acc = 0.f;
  if (n < 84) {
    const float* w = br ? w1 : w0;
    const float* wfp = wf + n * 168 + br * 84;
    const float* wp = w + c * 9 + tap;   // stride per oc = 128*9 = 1152
    for (int oc = 0; oc < 84; oc++) acc += wfp[oc] * wp[oc * 1152];
  }
  weffg[idx] = f2bf(acc);
}

// ---- kernel 3: fused deform-sample + GEMM -----------------------------------
// block per (b,h): 512 blocks, 256 threads (4 waves).
// M-tile = 64 pixels (w 0..63), N = 96 (84 padded), K = 2304 in 72 steps of 32.
// MFMA: A-operand = weff tile [16 o][32 k], B-operand = samples [32 k][16 px],
// so D rows = o, D cols = pixel -> coalesced stores along w.
__global__ __launch_bounds__(256, 2) void deform_main(
    const u16* __restrict__ xT, const u16* __restrict__ weffg,
    const float* __restrict__ dm0, const float* __restrict__ dm1,
    const float* __restrict__ bias, float* __restrict__ out) {
  __shared__ float dmL[2304];                       // [br][tap][yx][w]
  __shared__ __align__(16) u16 Abuf[2][64 * 40];    // samples, pitch 40 shorts
  __shared__ __align__(16) u16 Bbuf[2][96 * 40];    // weff, pitch 40 shorts

  const int t = threadIdx.x;
  const int bid = blockIdx.x;
  const int b = bid >> 6, h = bid & 63;

  // stage offsets for this (b,h) row
  for (int i = t; i < 2304; i += 256) {
    int br = i >= 1152 ? 1 : 0;
    int r = i - br * 1152;
    int ch = r >> 6, w = r & 63;
    const float* dm = br ? dm1 : dm0;
    dmL[i] = dm[(((size_t)b * 18 + ch) * 64 + h) * 64 + w];
  }
  __syncthreads();

  const int px = t & 63;       // pixel (w coordinate)
  const int cg = t >> 6;       // channel-quarter within k-step: 8 channels
  const u16* xb = xT + (size_t)b * 524288;

  f32x4 acc[6];
#pragma unroll
  for (int i = 0; i < 6; i++) acc[i] = f32x4{0.f, 0.f, 0.f, 0.f};

  // staging state (issued early, consumed next iteration)
  uint4 q00, q01, q10, q11, qb0, qb1;
  float w00, w01, w10, w11;

  auto issue = [&](int ks) {
    int br = ks >= 36 ? 1 : 0;
    int ksb = ks - br * 36;
    int tap = ksb >> 2, chunk = ksb & 3;
    float dy = dmL[br * 1152 + tap * 128 + px];
    float dx = dmL[br * 1152 + tap * 128 + 64 + px];
    float pyf = (float)(h + (tap / 3) - 1) + dy;
    float pxf = (float)(px + (tap % 3) - 1) + dx;
    float y0f = floorf(pyf), x0f = floorf(pxf);
    int y0 = (int)y0f, x0 = (int)x0f;
    float wy1 = pyf - y0f, wx1 = pxf - x0f;
    float wy0 = 1.f - wy1, wx0 = 1.f - wx1;
    int y1 = y0 + 1, x1 = x0 + 1;
    float my0 = ((u32)y0 < 64u) ? 1.f : 0.f;
    float my1 = ((u32)y1 < 64u) ? 1.f : 0.f;
    float mx0 = ((u32)x0 < 64u) ? 1.f : 0.f;
    float mx1 = ((u32)x1 < 64u) ? 1.f : 0.f;
    w00 = wy0 * wx0 * my0 * mx0;
    w01 = wy0 * wx1 * my0 * mx1;
    w10 = wy1 * wx0 * my1 * mx0;
    w11 = wy1 * wx1 * my1 * mx1;
    int y0c = min(63, max(0, y0)), y1c = min(63, max(0, y1));
    int x0c = min(63, max(0, x0)), x1c = min(63, max(0, x1));
    int c0 = chunk * 32 + cg * 8;
    const u16* r0 = xb + y0c * 8192 + c0;
    const u16* r1 = xb + y1c * 8192 + c0;
    q00 = *(const uint4*)(r0 + x0c * 128);
    q01 = *(const uint4*)(r0 + x1c * 128);
    q10 = *(const uint4*)(r1 + x0c * 128);
    q11 = *(const uint4*)(r1 + x1c * 128);
    // weff chunk(s): fully coalesced contiguous 6144B per k-step
    const u16* wp = weffg + ks * 3072;
    qb0 = *(const uint4*)(wp + t * 8);
    if (t < 128) qb1 = *(const uint4*)(wp + (256 + t) * 8);
  };

  auto write_stage = [&](int ks) {
    int buf = ks & 1;
    u32 rr[4];
#pragma unroll
    for (int j = 0; j < 4; j++) {
      u32 u0 = (&q00.x)[j], u1 = (&q01.x)[j], u2 = (&q10.x)[j], u3 = (&q11.x)[j];
      float lo = w00 * bflo(u0) + w01 * bflo(u1) + w10 * bflo(u2) + w11 * bflo(u3);
      float hi = w00 * bfhi(u0) + w01 * bfhi(u1) + w10 * bfhi(u2) + w11 * bfhi(u3);
      rr[j] = pack2(lo, hi);
    }
    uint4 r;
    r.x = rr[0]; r.y = rr[1]; r.z = rr[2]; r.w = rr[3];
    *(uint4*)&Abuf[buf][px * 40 + cg * 8] = r;
    // weff -> LDS (rows n, pitch 40)
    {
      int n = t >> 2, c16 = t & 3;
      *(uint4*)&Bbuf[buf][n * 40 + c16 * 8] = qb0;
    }
    if (t < 128) {
      int cid = 256 + t;
      int n = cid >> 2, c16 = cid & 3;
      *(uint4*)&Bbuf[buf][n * 40 + c16 * 8] = qb1;
    }
  };

  const int wv = t >> 6, lane = t & 63;
  const int lrow = lane & 15, lk = lane >> 4;
  const int aoff = (wv * 16 + lrow) * 40 + lk * 8;
  const int boff = lrow * 40 + lk * 8;

  issue(0);
  for (int ks = 0; ks < 72; ks++) {
    write_stage(ks);
    __syncthreads();
    if (ks < 71) issue(ks + 1);
    int buf = ks & 1;
    bf16x8 af = *(const bf16x8*)&Abuf[buf][aoff];
#pragma unroll
    for (int nt = 0; nt < 6; nt++) {
      bf16x8 wfr = *(const bf16x8*)&Bbuf[buf][nt * 640 + boff];
      acc[nt] = __builtin_amdgcn_mfma_f32_16x16x32_bf16(wfr, af, acc[nt], 0, 0, 0);
    }
  }

  // epilogue: D row = o (lk*4+j within tile), col = pixel (lrow)
  const int wpx = wv * 16 + lrow;
  float* op = out + (((size_t)b * 84) * 64 + h) * 64 + wpx;
#pragma unroll
  for (int nt = 0; nt < 6; nt++) {
#pragma unroll
    for (int j = 0; j < 4; j++) {
      int o = nt * 16 + lk * 4 + j;
      if (o < 84) op[(size_t)o * 4096] = acc[nt][j] + bias[o];
    }
  }
}

// ---- launch -----------------------------------------------------------------
extern "C" void kernel_launch(void* const* d_in, const int* in_sizes, int n_in,
                              void* d_out, int out_size, void* d_ws, size_t ws_size,
                              hipStream_t stream) {
  const float* x   = (const float*)d_in[0];
  const float* dm0 = (const float*)d_in[1];
  const float* dm1 = (const float*)d_in[2];
  const float* w0  = (const float*)d_in[3];
  const float* w1  = (const float*)d_in[4];
  const float* wf  = (const float*)d_in[5];
  const float* bf  = (const float*)d_in[6];
  float* out = (float*)d_out;

  u16* xT = (u16*)d_ws;                                    // 8 MiB
  u16* weffg = (u16*)((char*)d_ws + (size_t)8 * 64 * 64 * 128 * 2);  // 432 KiB

  transpose_k<<<512, 256, 0, stream>>>(x, xT);
  weff_k<<<864, 256, 0, stream>>>(w0, w1, wf, weffg);
  deform_main<<<512, 256, 0, stream>>>(xT, weffg, dm0, dm1, bf, out);
}

// Round 2
// 115.155 us; speedup vs baseline: 1.0280x; 1.0280x over previous
//
#include <hip/hip_runtime.h>
#include <hip/hip_bf16.h>

using u16 = unsigned short;
using u32 = unsigned int;
typedef float f32x4 __attribute__((ext_vector_type(4)));
typedef __bf16 bf16x8 __attribute__((ext_vector_type(8)));

// ---- helpers ----------------------------------------------------------------
static __device__ __forceinline__ float bflo(u32 u) { return __uint_as_float(u << 16); }
static __device__ __forceinline__ float bfhi(u32 u) { return __uint_as_float(u & 0xffff0000u); }

static __device__ __forceinline__ u32 pack2(float a, float b) {
  __hip_bfloat16 ha = __float2bfloat16(a);
  __hip_bfloat16 hb = __float2bfloat16(b);
  u16 ra, rb;
  __builtin_memcpy(&ra, &ha, 2);
  __builtin_memcpy(&rb, &hb, 2);
  return (u32)ra | ((u32)rb << 16);
}

static __device__ __forceinline__ u16 f2bf(float f) {
  u32 u = __float_as_uint(f);
  u32 r = (u + 0x7fffu + ((u >> 16) & 1u)) >> 16;
  return (u16)r;
}

static __device__ __forceinline__ bf16x8 as_bf(uint4 v) {
  bf16x8 r;
  __builtin_memcpy(&r, &v, 16);
  return r;
}

// ---- kernel 1: x [B,C,H,W] f32 -> xT [B,H,W,C] bf16 -------------------------
__global__ __launch_bounds__(256) void transpose_k(const float* __restrict__ x,
                                                   u16* __restrict__ xT) {
  const int bid = blockIdx.x;
  const int b = bid >> 6, y = bid & 63;
  const int t = threadIdx.x;
  const int cg = t >> 4;
  const int w16 = t & 15;
  const float* xp = x + ((size_t)(b * 128) * 64 + y) * 64;
  u16* op = xT + ((size_t)(b * 64 + y) * 64) * 128;
#pragma unroll
  for (int pass = 0; pass < 4; pass++) {
    int w = pass * 16 + w16;
    u32 rr[4];
#pragma unroll
    for (int jj = 0; jj < 4; jj++) {
      float a = xp[(cg * 8 + 2 * jj) * 4096 + w];
      float c = xp[(cg * 8 + 2 * jj + 1) * 4096 + w];
      rr[jj] = pack2(a, c);
    }
    uint4 r;
    r.x = rr[0]; r.y = rr[1]; r.z = rr[2]; r.w = rr[3];
    *(uint4*)(op + w * 128 + cg * 8) = r;
  }
}

// ---- kernel 2: weff in MFMA-A-fragment layout --------------------------------
// element index = ((ks*6 + nt)*64 + lane)*8 + j
//   n (=o) = nt*16 + (lane&15);  kc = (lane>>4)*8 + j   (kc in 0..31 within step)
// value = sum_oc wf[n, br*84+oc] * w_br[oc][c][tap],
//   ks: br = ks>=36, ksb = ks-36*br, tap = ksb>>2, chunk = ksb&3, c = chunk*32+kc
__global__ __launch_bounds__(256) void weff_k(const float* __restrict__ w0,
                                              const float* __restrict__ w1,
                                              const float* __restrict__ wf,
                                              u16* __restrict__ weffg) {
  const int idx = blockIdx.x * 256 + threadIdx.x;  // 221184 total
  const int j = idx & 7;
  const int l = (idx >> 3) & 63;
  const int rest = idx >> 9;       // ks*6 + nt, 0..431
  const int nt = rest % 6;
  const int ks = rest / 6;
  const int n = nt * 16 + (l & 15);
  const int kc = (l >> 4) * 8 + j;
  const int br = ks >= 36 ? 1 : 0;
  const int ksb = ks - br * 36;
  const int tap = ksb >> 2, chunk = ksb & 3;
  const int c = chunk * 32 + kc;
  float acc = 0.f;
  if (n < 84) {
    const float* w = br ? w1 : w0;
    const float* wfp = wf + n * 168 + br * 84;
    const float* wp = w + c * 9 + tap;   // stride per oc = 128*9 = 1152
    for (int oc = 0; oc < 84; oc++) acc += wfp[oc] * wp[oc * 1152];
  }
  weffg[idx] = f2bf(acc);
}

// ---- kernel 3: barrier-free fused deform-sample + GEMM ----------------------
// 1024 blocks (b = blk&7 for XCD-L2 pinning, then h, half-row), 256 threads.
// Wave wv: tile = wv&1 (16 px), br = wv>>1 (K-half). Each wave: 16px x 96out x K=1152,
// 36 k-steps of 32, all operands in registers (af built by bilinear blend,
// weff fragments loaded coalesced from global). No LDS/barriers in main loop.
// Final: branch-1 waves dump acc to LDS, branch-0 waves add + bias + store.
__global__ __launch_bounds__(256, 4) void deform_main(
    const u16* __restrict__ xT, const u16* __restrict__ weffg,
    const float* __restrict__ dm0, const float* __restrict__ dm1,
    const float* __restrict__ bias, float* __restrict__ out) {
  __shared__ float red[2][24][64];   // 12 KiB

  const int t = threadIdx.x;
  const int wv = t >> 6, lane = t & 63;
  const int tile = wv & 1, br = wv >> 1;
  const int blk = blockIdx.x;
  const int b = blk & 7;
  const int rem = blk >> 3;            // 0..127
  const int h = rem & 63;
  const int px0 = (rem >> 6) * 32 + tile * 16;
  const int px = px0 + (lane & 15);
  const int lg = lane >> 4;            // channel-group: channels lg*8..lg*8+7

  const u16* xb = xT + (size_t)b * 524288;
  const float* dm = (br ? dm1 : dm0) + (size_t)b * 73728 + h * 64 + px;  // + ch*4096
  const u16* wbase = weffg + (size_t)(br * 36) * 3072 + lane * 8;

  f32x4 acc[6];
#pragma unroll
  for (int i = 0; i < 6; i++) acc[i] = f32x4{0.f, 0.f, 0.f, 0.f};

  // tap state
  float w00, w01, w10, w11;
  int o00, o01, o10, o11;
  float dyN, dxN;
  uint4 q00, q01, q10, q11;   // corners in flight

  auto tapstate = [&](int tap, float dy, float dx) {
    int ty = tap / 3, tx = tap - ty * 3;
    float pyf = (float)(h + ty - 1) + dy;
    float pxf = (float)(px + tx - 1) + dx;
    float y0f = floorf(pyf), x0f = floorf(pxf);
    int y0 = (int)y0f, x0 = (int)x0f;
    float wy1 = pyf - y0f, wx1 = pxf - x0f;
    float wy0 = 1.f - wy1, wx0 = 1.f - wx1;
    int y1 = y0 + 1, x1 = x0 + 1;
    float my0 = ((u32)y0 < 64u) ? 1.f : 0.f;
    float my1 = ((u32)y1 < 64u) ? 1.f : 0.f;
    float mx0 = ((u32)x0 < 64u) ? 1.f : 0.f;
    float mx1 = ((u32)x1 < 64u) ? 1.f : 0.f;
    w00 = wy0 * wx0 * my0 * mx0;
    w01 = wy0 * wx1 * my0 * mx1;
    w10 = wy1 * wx0 * my1 * mx0;
    w11 = wy1 * wx1 * my1 * mx1;
    int y0c = min(63, max(0, y0)), y1c = min(63, max(0, y1));
    int x0c = min(63, max(0, x0)), x1c = min(63, max(0, x1));
    int r0 = y0c * 8192 + lg * 8, r1 = y1c * 8192 + lg * 8;
    o00 = r0 + x0c * 128; o01 = r0 + x1c * 128;
    o10 = r1 + x0c * 128; o11 = r1 + x1c * 128;
  };

  auto issue_corners = [&](int chunk) {
    int co = chunk * 32;
    q00 = *(const uint4*)(xb + o00 + co);
    q01 = *(const uint4*)(xb + o01 + co);
    q10 = *(const uint4*)(xb + o10 + co);
    q11 = *(const uint4*)(xb + o11 + co);
  };

  // prologue: tap 0 state, prefetch dm for tap 1, issue corners for ks=0
  {
    float dy0 = dm[0], dx0 = dm[4096];
    tapstate(0, dy0, dx0);
  }
  dyN = dm[2 * 4096]; dxN = dm[3 * 4096];
  issue_corners(0);

#pragma unroll 4
  for (int ks = 0; ks < 36; ks++) {
    // weff fragments for this step (coalesced 1KB/wave per nt, L1/L2-hot)
    const u16* wp = wbase + (size_t)ks * 3072;
    uint4 wq0 = *(const uint4*)(wp);
    uint4 wq1 = *(const uint4*)(wp + 512);
    uint4 wq2 = *(const uint4*)(wp + 1024);
    uint4 wq3 = *(const uint4*)(wp + 1536);
    uint4 wq4 = *(const uint4*)(wp + 2048);
    uint4 wq5 = *(const uint4*)(wp + 2560);

    // blend current corners -> af (B-operand fragment, in registers)
    uint4 afu;
    {
      u32 rr[4];
#pragma unroll
      for (int j = 0; j < 4; j++) {
        u32 u0 = (&q00.x)[j], u1 = (&q01.x)[j], u2 = (&q10.x)[j], u3 = (&q11.x)[j];
        float lo = w00 * bflo(u0) + w01 * bflo(u1) + w10 * bflo(u2) + w11 * bflo(u3);
        float hi = w00 * bfhi(u0) + w01 * bfhi(u1) + w10 * bfhi(u2) + w11 * bfhi(u3);
        rr[j] = pack2(lo, hi);
      }
      afu.x = rr[0]; afu.y = rr[1]; afu.z = rr[2]; afu.w = rr[3];
    }

    // prefetch next step's corners (and tap state at boundaries)
    int nk = ks + 1;
    if (nk < 36) {
      if ((nk & 3) == 0) {
        tapstate(nk >> 2, dyN, dxN);
        int tn = (nk >> 2) + 1;
        if (tn < 9) { dyN = dm[(2 * tn) * 4096]; dxN = dm[(2 * tn + 1) * 4096]; }
      }
      issue_corners(nk & 3);
    }

    bf16x8 af = as_bf(afu);
    acc[0] = __builtin_amdgcn_mfma_f32_16x16x32_bf16(as_bf(wq0), af, acc[0], 0, 0, 0);
    acc[1] = __builtin_amdgcn_mfma_f32_16x16x32_bf16(as_bf(wq1), af, acc[1], 0, 0, 0);
    acc[2] = __builtin_amdgcn_mfma_f32_16x16x32_bf16(as_bf(wq2), af, acc[2], 0, 0, 0);
    acc[3] = __builtin_amdgcn_mfma_f32_16x16x32_bf16(as_bf(wq3), af, acc[3], 0, 0, 0);
    acc[4] = __builtin_amdgcn_mfma_f32_16x16x32_bf16(as_bf(wq4), af, acc[4], 0, 0, 0);
    acc[5] = __builtin_amdgcn_mfma_f32_16x16x32_bf16(as_bf(wq5), af, acc[5], 0, 0, 0);
  }

  // cross-branch reduction in LDS, then store (branch-0 waves)
  if (br == 1) {
#pragma unroll
    for (int nt = 0; nt < 6; nt++)
#pragma unroll
      for (int j = 0; j < 4; j++) red[tile][nt * 4 + j][lane] = acc[nt][j];
  }
  __syncthreads();
  if (br == 0) {
    float* op = out + ((size_t)b * 84 * 64 + h) * 64 + px;
#pragma unroll
    for (int nt = 0; nt < 6; nt++) {
#pragma unroll
      for (int j = 0; j < 4; j++) {
        int o = nt * 16 + lg * 4 + j;
        if (o < 84)
          op[(size_t)o * 4096] = acc[nt][j] + red[tile][nt * 4 + j][lane] + bias[o];
      }
    }
  }
}

// ---- launch -----------------------------------------------------------------
extern "C" void kernel_launch(void* const* d_in, const int* in_sizes, int n_in,
                              void* d_out, int out_size, void* d_ws, size_t ws_size,
                              hipStream_t stream) {
  const float* x   = (const float*)d_in[0];
  const float* dm0 = (const float*)d_in[1];
  const float* dm1 = (const float*)d_in[2];
  const float* w0  = (const float*)d_in[3];
  const float* w1  = (const float*)d_in[4];
  const float* wf  = (const float*)d_in[5];
  const float* bf  = (const float*)d_in[6];
  float* out = (float*)d_out;

  u16* xT = (u16*)d_ws;                                               // 8 MiB
  u16* weffg = (u16*)((char*)d_ws + (size_t)8 * 64 * 64 * 128 * 2);   // 432 KiB

  transpose_k<<<512, 256, 0, stream>>>(x, xT);
  weff_k<<<864, 256, 0, stream>>>(w0, w1, wf, weffg);
  deform_main<<<1024, 256, 0, stream>>>(xT, weffg, dm0, dm1, bf, out);
}

// Round 3
// 99.322 us; speedup vs baseline: 1.1919x; 1.1594x over previous
//
#include <hip/hip_runtime.h>
#include <hip/hip_bf16.h>

using u16 = unsigned short;
using u32 = unsigned int;
typedef float f32x4 __attribute__((ext_vector_type(4)));
typedef __bf16 bf16x8 __attribute__((ext_vector_type(8)));

// ---- helpers ----------------------------------------------------------------
static __device__ __forceinline__ float bflo(u32 u) { return __uint_as_float(u << 16); }
static __device__ __forceinline__ float bfhi(u32 u) { return __uint_as_float(u & 0xffff0000u); }

static __device__ __forceinline__ u32 pack2(float a, float b) {
  __hip_bfloat16 ha = __float2bfloat16(a);
  __hip_bfloat16 hb = __float2bfloat16(b);
  u16 ra, rb;
  __builtin_memcpy(&ra, &ha, 2);
  __builtin_memcpy(&rb, &hb, 2);
  return (u32)ra | ((u32)rb << 16);
}

static __device__ __forceinline__ u16 f2bf(float f) {
  u32 u = __float_as_uint(f);
  u32 r = (u + 0x7fffu + ((u >> 16) & 1u)) >> 16;
  return (u16)r;
}

static __device__ __forceinline__ bf16x8 as_bf(uint4 v) {
  bf16x8 r;
  __builtin_memcpy(&r, &v, 16);
  return r;
}

// 4-corner bilinear blend of 8 bf16 channels -> bf16x8 fragment (as uint4)
static __device__ __forceinline__ uint4 blend4(uint4 a, uint4 b, uint4 c, uint4 d,
                                               float w00, float w01, float w10, float w11) {
  u32 rr[4];
#pragma unroll
  for (int j = 0; j < 4; j++) {
    u32 u0 = (&a.x)[j], u1 = (&b.x)[j], u2 = (&c.x)[j], u3 = (&d.x)[j];
    float lo = w00 * bflo(u0) + w01 * bflo(u1) + w10 * bflo(u2) + w11 * bflo(u3);
    float hi = w00 * bfhi(u0) + w01 * bfhi(u1) + w10 * bfhi(u2) + w11 * bfhi(u3);
    rr[j] = pack2(lo, hi);
  }
  uint4 r;
  r.x = rr[0]; r.y = rr[1]; r.z = rr[2]; r.w = rr[3];
  return r;
}

// ---- kernel 1: x [B,C,H,W] f32 -> xT [B,H,W,C] bf16 -------------------------
__global__ __launch_bounds__(256) void transpose_k(const float* __restrict__ x,
                                                   u16* __restrict__ xT) {
  const int bid = blockIdx.x;
  const int b = bid >> 6, y = bid & 63;
  const int t = threadIdx.x;
  const int cg = t >> 4;
  const int w16 = t & 15;
  const float* xp = x + ((size_t)(b * 128) * 64 + y) * 64;
  u16* op = xT + ((size_t)(b * 64 + y) * 64) * 128;
#pragma unroll
  for (int pass = 0; pass < 4; pass++) {
    int w = pass * 16 + w16;
    u32 rr[4];
#pragma unroll
    for (int jj = 0; jj < 4; jj++) {
      float a = xp[(cg * 8 + 2 * jj) * 4096 + w];
      float c = xp[(cg * 8 + 2 * jj + 1) * 4096 + w];
      rr[jj] = pack2(a, c);
    }
    uint4 r;
    r.x = rr[0]; r.y = rr[1]; r.z = rr[2]; r.w = rr[3];
    *(uint4*)(op + w * 128 + cg * 8) = r;
  }
}

// ---- kernel 2: weff in MFMA-A-fragment layout --------------------------------
// element index = ((ks*6 + nt)*64 + lane)*8 + j
//   n (=o) = nt*16 + (lane&15);  kc = (lane>>4)*8 + j
// ks: br = ks>=36, ksb = ks-36*br, tap = ksb>>2, chunk = ksb&3, c = chunk*32+kc
__global__ __launch_bounds__(256) void weff_k(const float* __restrict__ w0,
                                              const float* __restrict__ w1,
                                              const float* __restrict__ wf,
                                              u16* __restrict__ weffg) {
  const int idx = blockIdx.x * 256 + threadIdx.x;  // 221184 total
  const int j = idx & 7;
  const int l = (idx >> 3) & 63;
  const int rest = idx >> 9;       // ks*6 + nt, 0..431
  const int nt = rest % 6;
  const int ks = rest / 6;
  const int n = nt * 16 + (l & 15);
  const int kc = (l >> 4) * 8 + j;
  const int br = ks >= 36 ? 1 : 0;
  const int ksb = ks - br * 36;
  const int tap = ksb >> 2, chunk = ksb & 3;
  const int c = chunk * 32 + kc;
  float acc = 0.f;
  if (n < 84) {
    const float* w = br ? w1 : w0;
    const float* wfp = wf + n * 168 + br * 84;
    const float* wp = w + c * 9 + tap;   // stride per oc = 128*9 = 1152
#pragma unroll 4
    for (int oc = 0; oc < 84; oc++) acc += wfp[oc] * wp[oc * 1152];
  }
  weffg[idx] = f2bf(acc);
}

// ---- kernel 3: fused deform-sample + GEMM, M=64/wave, K/4 split -------------
// 512 blocks = (b:8 -> XCD) x (h:64). 4 waves: br = wv>>1 (branch), cp = wv&1
// (chunk-pair -> channels cp*64 + c*32). Wave: 64 px x 96 out x K=576
// (9 taps x 2 chunk-steps of 32). Per step: 16 corner gathers (4 frags) +
// 6 weff loads + 24 MFMA, all register-resident, no barriers in main loop.
// End: LDS tree-reduction across the 4 K-partials, bias, store.
__global__ __launch_bounds__(256, 2) void deform_main(
    const u16* __restrict__ xT, const u16* __restrict__ weffg,
    const float* __restrict__ dm0, const float* __restrict__ dm1,
    const float* __restrict__ bias, float* __restrict__ out) {
  __shared__ f32x4 red[2][6][4][64];   // 48 KiB

  const int t = threadIdx.x;
  const int wv = t >> 6, lane = t & 63;
  const int br = wv >> 1, cp = wv & 1;
  const int lrow = lane & 15, lg = lane >> 4;
  const int blk = blockIdx.x;
  const int b = blk & 7, h = blk >> 3;

  const u16* xb = xT + (size_t)b * 524288;
  const float* dmb = (br ? dm1 : dm0) + (size_t)b * 73728 + h * 64;
  const u16* wbase = weffg + ((size_t)(br * 36 + cp * 2)) * 3072 + lane * 8;
  const int cb = cp * 64 + lg * 8;   // channel base within 128 for this lane

  f32x4 acc[6][4];
#pragma unroll
  for (int i = 0; i < 6; i++)
#pragma unroll
    for (int f = 0; f < 4; f++) acc[i][f] = f32x4{0.f, 0.f, 0.f, 0.f};

  // dm values for current tap (prefetched)
  float dyC[4], dxC[4];
#pragma unroll
  for (int f = 0; f < 4; f++) {
    dyC[f] = dmb[0 * 4096 + f * 16 + lrow];
    dxC[f] = dmb[1 * 4096 + f * 16 + lrow];
  }

  int r0a[4], r1a[4], xo0a[4], xo1a[4];
  float wy0a[4], wy1a[4], wx0a[4], wx1a[4];

#pragma unroll 1
  for (int tap = 0; tap < 9; tap++) {
    const int ty = (tap * 11) >> 5;        // tap/3 for 0..8
    const int tx = tap - ty * 3;
    // tap state for the 4 pixel-fragments
#pragma unroll
    for (int f = 0; f < 4; f++) {
      float pyf = (float)(h + ty - 1) + dyC[f];
      float pxf = (float)(f * 16 + lrow + tx - 1) + dxC[f];
      float y0f = floorf(pyf), x0f = floorf(pxf);
      int y0 = (int)y0f, x0 = (int)x0f;
      float wy1 = pyf - y0f, wx1 = pxf - x0f;
      int y1 = y0 + 1, x1 = x0 + 1;
      wy0a[f] = (1.f - wy1) * (((u32)y0 < 64u) ? 1.f : 0.f);
      wy1a[f] = wy1 * (((u32)y1 < 64u) ? 1.f : 0.f);
      wx0a[f] = (1.f - wx1) * (((u32)x0 < 64u) ? 1.f : 0.f);
      wx1a[f] = wx1 * (((u32)x1 < 64u) ? 1.f : 0.f);
      int y0c = min(63, max(0, y0)), y1c = min(63, max(0, y1));
      int x0c = min(63, max(0, x0)), x1c = min(63, max(0, x1));
      r0a[f] = y0c * 8192 + cb;
      r1a[f] = y1c * 8192 + cb;
      xo0a[f] = x0c * 128;
      xo1a[f] = x1c * 128;
    }
    // prefetch next tap's dm (in flight across both chunk-steps)
    if (tap < 8) {
#pragma unroll
      for (int f = 0; f < 4; f++) {
        dyC[f] = dmb[(2 * tap + 2) * 4096 + f * 16 + lrow];
        dxC[f] = dmb[(2 * tap + 3) * 4096 + f * 16 + lrow];
      }
    }

#pragma unroll
    for (int c = 0; c < 2; c++) {
      const u16* wp = wbase + (size_t)(tap * 4 + c) * 3072;
      uint4 wq0 = *(const uint4*)(wp);
      uint4 wq1 = *(const uint4*)(wp + 512);
      uint4 wq2 = *(const uint4*)(wp + 1024);
      uint4 wq3 = *(const uint4*)(wp + 1536);
      uint4 wq4 = *(const uint4*)(wp + 2048);
      uint4 wq5 = *(const uint4*)(wp + 2560);
      const int co = c * 32;

      // half 0: frags 0,1 — issue 8 gathers
      uint4 qa[8];
#pragma unroll
      for (int f = 0; f < 2; f++) {
        qa[f * 4 + 0] = *(const uint4*)(xb + r0a[f] + xo0a[f] + co);
        qa[f * 4 + 1] = *(const uint4*)(xb + r0a[f] + xo1a[f] + co);
        qa[f * 4 + 2] = *(const uint4*)(xb + r1a[f] + xo0a[f] + co);
        qa[f * 4 + 3] = *(const uint4*)(xb + r1a[f] + xo1a[f] + co);
      }
      // blend half 0
      uint4 af0u, af1u;
      {
        float w00 = wy0a[0] * wx0a[0], w01 = wy0a[0] * wx1a[0];
        float w10 = wy1a[0] * wx0a[0], w11 = wy1a[0] * wx1a[0];
        af0u = blend4(qa[0], qa[1], qa[2], qa[3], w00, w01, w10, w11);
        float v00 = wy0a[1] * wx0a[1], v01 = wy0a[1] * wx1a[1];
        float v10 = wy1a[1] * wx0a[1], v11 = wy1a[1] * wx1a[1];
        af1u = blend4(qa[4], qa[5], qa[6], qa[7], v00, v01, v10, v11);
      }
      // half 1: frags 2,3 — issue 8 gathers (latency hidden under MFMAs below)
      uint4 qb[8];
#pragma unroll
      for (int f = 0; f < 2; f++) {
        int g = f + 2;
        qb[f * 4 + 0] = *(const uint4*)(xb + r0a[g] + xo0a[g] + co);
        qb[f * 4 + 1] = *(const uint4*)(xb + r0a[g] + xo1a[g] + co);
        qb[f * 4 + 2] = *(const uint4*)(xb + r1a[g] + xo0a[g] + co);
        qb[f * 4 + 3] = *(const uint4*)(xb + r1a[g] + xo1a[g] + co);
      }

      bf16x8 af0 = as_bf(af0u), af1 = as_bf(af1u);
      __builtin_amdgcn_s_setprio(1);
      acc[0][0] = __builtin_amdgcn_mfma_f32_16x16x32_bf16(as_bf(wq0), af0, acc[0][0], 0, 0, 0);
      acc[1][0] = __builtin_amdgcn_mfma_f32_16x16x32_bf16(as_bf(wq1), af0, acc[1][0], 0, 0, 0);
      acc[2][0] = __builtin_amdgcn_mfma_f32_16x16x32_bf16(as_bf(wq2), af0, acc[2][0], 0, 0, 0);
      acc[3][0] = __builtin_amdgcn_mfma_f32_16x16x32_bf16(as_bf(wq3), af0, acc[3][0], 0, 0, 0);
      acc[4][0] = __builtin_amdgcn_mfma_f32_16x16x32_bf16(as_bf(wq4), af0, acc[4][0], 0, 0, 0);
      acc[5][0] = __builtin_amdgcn_mfma_f32_16x16x32_bf16(as_bf(wq5), af0, acc[5][0], 0, 0, 0);
      acc[0][1] = __builtin_amdgcn_mfma_f32_16x16x32_bf16(as_bf(wq0), af1, acc[0][1], 0, 0, 0);
      acc[1][1] = __builtin_amdgcn_mfma_f32_16x16x32_bf16(as_bf(wq1), af1, acc[1][1], 0, 0, 0);
      acc[2][1] = __builtin_amdgcn_mfma_f32_16x16x32_bf16(as_bf(wq2), af1, acc[2][1], 0, 0, 0);
      acc[3][1] = __builtin_amdgcn_mfma_f32_16x16x32_bf16(as_bf(wq3), af1, acc[3][1], 0, 0, 0);
      acc[4][1] = __builtin_amdgcn_mfma_f32_16x16x32_bf16(as_bf(wq4), af1, acc[4][1], 0, 0, 0);
      acc[5][1] = __builtin_amdgcn_mfma_f32_16x16x32_bf16(as_bf(wq5), af1, acc[5][1], 0, 0, 0);
      __builtin_amdgcn_s_setprio(0);

      // blend half 1
      uint4 af2u, af3u;
      {
        float w00 = wy0a[2] * wx0a[2], w01 = wy0a[2] * wx1a[2];
        float w10 = wy1a[2] * wx0a[2], w11 = wy1a[2] * wx1a[2];
        af2u = blend4(qb[0], qb[1], qb[2], qb[3], w00, w01, w10, w11);
        float v00 = wy0a[3] * wx0a[3], v01 = wy0a[3] * wx1a[3];
        float v10 = wy1a[3] * wx0a[3], v11 = wy1a[3] * wx1a[3];
        af3u = blend4(qb[4], qb[5], qb[6], qb[7], v00, v01, v10, v11);
      }
      bf16x8 af2 = as_bf(af2u), af3 = as_bf(af3u);
      __builtin_amdgcn_s_setprio(1);
      acc[0][2] = __builtin_amdgcn_mfma_f32_16x16x32_bf16(as_bf(wq0), af2, acc[0][2], 0, 0, 0);
      acc[1][2] = __builtin_amdgcn_mfma_f32_16x16x32_bf16(as_bf(wq1), af2, acc[1][2], 0, 0, 0);
      acc[2][2] = __builtin_amdgcn_mfma_f32_16x16x32_bf16(as_bf(wq2), af2, acc[2][2], 0, 0, 0);
      acc[3][2] = __builtin_amdgcn_mfma_f32_16x16x32_bf16(as_bf(wq3), af2, acc[3][2], 0, 0, 0);
      acc[4][2] = __builtin_amdgcn_mfma_f32_16x16x32_bf16(as_bf(wq4), af2, acc[4][2], 0, 0, 0);
      acc[5][2] = __builtin_amdgcn_mfma_f32_16x16x32_bf16(as_bf(wq5), af2, acc[5][2], 0, 0, 0);
      acc[0][3] = __builtin_amdgcn_mfma_f32_16x16x32_bf16(as_bf(wq0), af3, acc[0][3], 0, 0, 0);
      acc[1][3] = __builtin_amdgcn_mfma_f32_16x16x32_bf16(as_bf(wq1), af3, acc[1][3], 0, 0, 0);
      acc[2][3] = __builtin_amdgcn_mfma_f32_16x16x32_bf16(as_bf(wq2), af3, acc[2][3], 0, 0, 0);
      acc[3][3] = __builtin_amdgcn_mfma_f32_16x16x32_bf16(as_bf(wq3), af3, acc[3][3], 0, 0, 0);
      acc[4][3] = __builtin_amdgcn_mfma_f32_16x16x32_bf16(as_bf(wq4), af3, acc[4][3], 0, 0, 0);
      acc[5][3] = __builtin_amdgcn_mfma_f32_16x16x32_bf16(as_bf(wq5), af3, acc[5][3], 0, 0, 0);
      __builtin_amdgcn_s_setprio(0);
    }
  }

  // ---- reduce the 4 K-partials across waves, then store ----
  if (wv >= 2) {
#pragma unroll
    for (int nt = 0; nt < 6; nt++)
#pragma unroll
      for (int f = 0; f < 4; f++) red[wv - 2][nt][f][lane] = acc[nt][f];
  }
  __syncthreads();
  if (wv == 1) {
#pragma unroll
    for (int nt = 0; nt < 6; nt++)
#pragma unroll
      for (int f = 0; f < 4; f++) {
        f32x4 v = red[1][nt][f][lane];
#pragma unroll
        for (int j = 0; j < 4; j++) acc[nt][f][j] += v[j];
        red[1][nt][f][lane] = acc[nt][f];
      }
  }
  if (wv == 0) {
#pragma unroll
    for (int nt = 0; nt < 6; nt++)
#pragma unroll
      for (int f = 0; f < 4; f++) {
        f32x4 v = red[0][nt][f][lane];
#pragma unroll
        for (int j = 0; j < 4; j++) acc[nt][f][j] += v[j];
      }
  }
  __syncthreads();
  if (wv == 0) {
    float* op = out + ((size_t)b * 84 * 64 + h) * 64;
#pragma unroll
    for (int nt = 0; nt < 6; nt++)
#pragma unroll
      for (int f = 0; f < 4; f++) {
        f32x4 v = red[1][nt][f][lane];
#pragma unroll
        for (int j = 0; j < 4; j++) acc[nt][f][j] += v[j];
      }
#pragma unroll
    for (int nt = 0; nt < 6; nt++)
#pragma unroll
      for (int j = 0; j < 4; j++) {
        int o = nt * 16 + lg * 4 + j;
        if (o < 84) {
          float bv = bias[o];
#pragma unroll
          for (int f = 0; f < 4; f++)
            op[(size_t)o * 4096 + f * 16 + lrow] = acc[nt][f][j] + bv;
        }
      }
  }
}

// ---- launch -----------------------------------------------------------------
extern "C" void kernel_launch(void* const* d_in, const int* in_sizes, int n_in,
                              void* d_out, int out_size, void* d_ws, size_t ws_size,
                              hipStream_t stream) {
  const float* x   = (const float*)d_in[0];
  const float* dm0 = (const float*)d_in[1];
  const float* dm1 = (const float*)d_in[2];
  const float* w0  = (const float*)d_in[3];
  const float* w1  = (const float*)d_in[4];
  const float* wf  = (const float*)d_in[5];
  const float* bf  = (const float*)d_in[6];
  float* out = (float*)d_out;

  u16* xT = (u16*)d_ws;                                               // 8 MiB
  u16* weffg = (u16*)((char*)d_ws + (size_t)8 * 64 * 64 * 128 * 2);   // 432 KiB

  transpose_k<<<512, 256, 0, stream>>>(x, xT);
  weff_k<<<864, 256, 0, stream>>>(w0, w1, wf, weffg);
  deform_main<<<512, 256, 0, stream>>>(xT, weffg, dm0, dm1, bf, out);
}